// Round 1
// baseline (1180.590 us; speedup 1.0000x reference)
//
#include <hip/hip_runtime.h>

// MetaPath2Vec loss:
//   pos_loss = mean(-log(sigmoid(dot) + 1e-15))  over 200000*6 dots
//   neg_loss = mean(-log(1 - sigmoid(dot) + 1e-15)) over 1000000*6 dots
//   out = pos_loss + neg_loss  (scalar f32)
// Memory-bound gather: 1.2M rows x 7 x 512B = 4.3 GB reads.

constexpr int DIM = 128;   // embedding dim (128 floats = 32 lanes * float4)
constexpr int CTX = 7;     // walk length (1 start + 6 contexts)

__global__ void zero_ws_kernel(double* ws) {
    if (threadIdx.x < 2) ws[threadIdx.x] = 0.0;
}

__global__ __launch_bounds__(256) void mp2v_loss_kernel(
    const float* __restrict__ emb,
    const int*   __restrict__ pos_rw,
    const int*   __restrict__ neg_rw,
    double*      __restrict__ ws,
    int pos_rows, int neg_rows)
{
    const int lane31        = threadIdx.x & 31;          // lane within 32-group
    const int groupInBlock  = threadIdx.x >> 5;          // 0..7 for 256 threads
    const int group         = (blockIdx.x * blockDim.x + threadIdx.x) >> 5;
    const int ngroups       = (gridDim.x * blockDim.x) >> 5;
    const int total         = pos_rows + neg_rows;
    const int halfBase      = threadIdx.x & 32;          // 0 or 32: wave-half base lane

    double accPos = 0.0, accNeg = 0.0;

    for (int row = group; row < total; row += ngroups) {
        const bool isPos = row < pos_rows;
        const int* rw = isPos ? pos_rw + (size_t)row * CTX
                              : neg_rw + (size_t)(row - pos_rows) * CTX;

        // lanes 0..6 of each half-wave load the 7 indices, broadcast by shuffle
        int myidx = (lane31 < CTX) ? rw[lane31] : 0;

        int idx0 = __shfl(myidx, halfBase + 0, 64);
        const float4* v0 = (const float4*)(emb + (size_t)idx0 * DIM);
        float4 h0 = v0[lane31];     // 32 lanes x 16B = full coalesced 512B row

        float rowLoss = 0.0f;       // valid on lane31==0 only
        #pragma unroll
        for (int j = 1; j < CTX; ++j) {
            int idx = __shfl(myidx, halfBase + j, 64);
            const float4* v = (const float4*)(emb + (size_t)idx * DIM);
            float4 c = v[lane31];
            float p = h0.x * c.x + h0.y * c.y + h0.z * c.z + h0.w * c.w;
            // reduce across the 32-lane group -> lane 0 of the group
            p += __shfl_down(p, 16, 32);
            p += __shfl_down(p, 8, 32);
            p += __shfl_down(p, 4, 32);
            p += __shfl_down(p, 2, 32);
            p += __shfl_down(p, 1, 32);
            // compute loss on all lanes (cheap; only lane0's value is used)
            float x = p;
            float s;
            if (x >= 0.0f) {
                s = 1.0f / (1.0f + expf(-x));
            } else {
                float e = expf(x);
                s = e / (1.0f + e);
            }
            float t = isPos ? (s + 1e-15f) : (1.0f - s + 1e-15f);
            rowLoss += -logf(t);
        }
        if (lane31 == 0) {
            if (isPos) accPos += (double)rowLoss;
            else       accNeg += (double)rowLoss;
        }
    }

    // block reduction: one pair of doubles per 32-group
    __shared__ double sPos[8];
    __shared__ double sNeg[8];
    if (lane31 == 0) { sPos[groupInBlock] = accPos; sNeg[groupInBlock] = accNeg; }
    __syncthreads();
    if (threadIdx.x == 0) {
        double p = 0.0, n = 0.0;
        #pragma unroll
        for (int i = 0; i < 8; ++i) { p += sPos[i]; n += sNeg[i]; }
        atomicAdd(&ws[0], p);
        atomicAdd(&ws[1], n);
    }
}

__global__ void finalize_kernel(const double* __restrict__ ws,
                                float* __restrict__ out,
                                double invPosCnt, double invNegCnt)
{
    out[0] = (float)(ws[0] * invPosCnt + ws[1] * invNegCnt);
}

extern "C" void kernel_launch(void* const* d_in, const int* in_sizes, int n_in,
                              void* d_out, int out_size, void* d_ws, size_t ws_size,
                              hipStream_t stream)
{
    const float* emb    = (const float*)d_in[0];
    const int*   pos_rw = (const int*)d_in[1];
    const int*   neg_rw = (const int*)d_in[2];
    float*       out    = (float*)d_out;
    double*      ws     = (double*)d_ws;

    const int pos_rows = in_sizes[1] / CTX;   // 200000
    const int neg_rows = in_sizes[2] / CTX;   // 1000000

    hipLaunchKernelGGL(zero_ws_kernel, dim3(1), dim3(64), 0, stream, ws);

    const int blocks = 4096;   // grid-stride; ~16 blocks/CU of 256 threads
    hipLaunchKernelGGL(mp2v_loss_kernel, dim3(blocks), dim3(256), 0, stream,
                       emb, pos_rw, neg_rw, ws, pos_rows, neg_rows);

    hipLaunchKernelGGL(finalize_kernel, dim3(1), dim3(1), 0, stream,
                       ws, out,
                       1.0 / (6.0 * (double)pos_rows),
                       1.0 / (6.0 * (double)neg_rows));
}